// Round 8
// baseline (2368.712 us; speedup 1.0000x reference)
//
#include <hip/hip_runtime.h>

#define B 2
#define NQ 4096
#define NA 2048
#define CH 512   // attention chunk (16 chunks)
#define LDK 40   // LDS row stride (shorts) — breaks bank conflicts of stride 32

typedef __attribute__((ext_vector_type(8))) short bf16x8;
typedef __attribute__((ext_vector_type(4))) float f32x4;

__device__ __forceinline__ float b2f(unsigned short u){ union{unsigned i; float f;} c; c.i=((unsigned)u)<<16; return c.f; }
__device__ __forceinline__ unsigned short f2b(float f){ union{float f; unsigned u;} c; c.f=f; unsigned u=c.u; u += 0x7FFFu + ((u>>16)&1u); return (unsigned short)(u>>16); }
__device__ __forceinline__ void split2(float x, short& h, short& l){
    unsigned short hh = f2b(x); h = (short)hh; l = (short)f2b(x - b2f(hh));
}

// ======================= small projections =======================
__global__ __launch_bounds__(256) void proj_small(
    const float* __restrict__ gf,
    const float* __restrict__ w_qs, const float* __restrict__ w_kg, const float* __restrict__ w_vg,
    float* __restrict__ q_attn, float* __restrict__ kgv, float* __restrict__ vgv)
{
    int mat = blockIdx.x >> 1, b = blockIdx.x & 1;
    const float* W = (mat==0) ? w_qs : (mat==1 ? w_kg : w_vg);
    float* O       = (mat==0) ? q_attn : (mat==1 ? kgv : vgv);
    __shared__ float sg[512];
    int t = threadIdx.x;
    for (int i=t;i<512;i+=256) sg[i] = gf[b*512+i];
    __syncthreads();
    for (int c=t;c<512;c+=256) {
        float acc = 0.f;
        for (int k=0;k<512;k++) acc = fmaf(sg[k], W[k*512+c], acc);
        O[b*512+c] = acc;
    }
}

// ======================= KNN: parallel top-8 (f64 exact), bank-conflict-free =======================
__global__ __launch_bounds__(256) void knn_kernel(
    const float* __restrict__ xyz_q, const float* __restrict__ axyz, int* __restrict__ knn)
{
    __shared__ float4 sa[NA];           // 32 KB
    __shared__ double cd[32*65];        // padded rows: bank stride 2 (free)
    __shared__ int    ci[32*65];
    const int t = threadIdx.x;
    const int b  = blockIdx.x >> 7;
    const int qi = t >> 3;                               // 0..31 query-in-block
    const int q  = ((blockIdx.x & 127) << 5) + qi;
    const int g  = t & 7;
    for (int i=t;i<NA;i+=256) {
        const float* ap = axyz + (size_t)(b*NA+i)*3;
        sa[i] = make_float4(ap[0],ap[1],ap[2],0.f);
    }
    __syncthreads();
    const double qx = (double)xyz_q[(size_t)(b*NQ+q)*3+0];
    const double qy = (double)xyz_q[(size_t)(b*NQ+q)*3+1];
    const double qz = (double)xyz_q[(size_t)(b*NQ+q)*3+2];
    const double qq = (qx*qx + qy*qy) + qz*qz;
    double best[8]; int bid[8];
    #pragma unroll
    for (int j=0;j<8;j++){ best[j]=1.0e300; bid[j]=0; }
    for (int jj=0; jj<256; jj++) {
        const int i = jj*8 + g;          // interleaved: banks 4g, broadcast across queries
        float4 a = sa[i];
        double ax=(double)a.x, ay=(double)a.y, az=(double)a.z;
        double aa  = (ax*ax + ay*ay) + az*az;
        double dot = (qx*ax + qy*ay) + qz*az;
        double dd  = (qq + aa) - 2.0*dot;
        if (dd < best[7]) {
            best[7]=dd; bid[7]=i;
            #pragma unroll
            for (int j=7;j>0;--j) if (best[j] < best[j-1]) {
                double tf=best[j]; best[j]=best[j-1]; best[j-1]=tf;
                int ti=bid[j]; bid[j]=bid[j-1]; bid[j-1]=ti;
            }
        }
    }
    const int cbase = qi*65 + g*8;
    #pragma unroll
    for (int j=0;j<8;j++){ cd[cbase+j]=best[j]; ci[cbase+j]=bid[j]; }
    __syncthreads();
    if (g==0) {
        double fb[8]; int fi[8];
        #pragma unroll
        for (int j=0;j<8;j++){ fb[j]=1.0e300; fi[j]=0; }
        const int c0 = qi*65;
        for (int c=c0; c<c0+64; c++) {
            double d = cd[c];
            if (d < fb[7]) {
                fb[7]=d; fi[7]=ci[c];
                #pragma unroll
                for (int j=7;j>0;--j) if (fb[j] < fb[j-1]) {
                    double tf=fb[j]; fb[j]=fb[j-1]; fb[j-1]=tf;
                    int ti=fi[j]; fi[j]=fi[j-1]; fi[j-1]=ti;
                }
            }
        }
        #pragma unroll
        for (int j=0;j<8;j++) knn[(size_t)(b*NQ+q)*8+j] = fi[j];
    }
}

// ======================= weight prep: W[k][n] fp32 -> [n][k] hi/lo bf16 =======================
__global__ __launch_bounds__(256) void prep_w(
    const float* __restrict__ W, short* __restrict__ Wh, short* __restrict__ Wl)
{
    const int gid = blockIdx.x*256 + threadIdx.x;
    const int n  = gid & 511;
    const int kc = (gid >> 9) * 8;
    short hi[8], lo[8];
    #pragma unroll
    for (int j=0;j<8;j++) split2(W[(size_t)(kc+j)*512 + n], hi[j], lo[j]);
    *(short4*)&Wh[(size_t)n*512 + kc]     = make_short4(hi[0],hi[1],hi[2],hi[3]);
    *(short4*)&Wh[(size_t)n*512 + kc + 4] = make_short4(hi[4],hi[5],hi[6],hi[7]);
    *(short4*)&Wl[(size_t)n*512 + kc]     = make_short4(lo[0],lo[1],lo[2],lo[3]);
    *(short4*)&Wl[(size_t)n*512 + kc + 4] = make_short4(lo[4],lo[5],lo[6],lo[7]);
}

// ======================= activation split: fp32 -> hi/lo bf16 =======================
__global__ __launch_bounds__(256) void split_fp32(
    const float* __restrict__ X, short* __restrict__ Xh, short* __restrict__ Xl)
{
    const size_t i0 = ((size_t)blockIdx.x*256 + threadIdx.x)*8;
    float4 a = *(const float4*)(X+i0), bq = *(const float4*)(X+i0+4);
    float v[8] = {a.x,a.y,a.z,a.w,bq.x,bq.y,bq.z,bq.w};
    short h[8], l[8];
    #pragma unroll
    for (int j=0;j<8;j++) split2(v[j], h[j], l[j]);
    *(short4*)(Xh+i0)   = make_short4(h[0],h[1],h[2],h[3]);
    *(short4*)(Xh+i0+4) = make_short4(h[4],h[5],h[6],h[7]);
    *(short4*)(Xl+i0)   = make_short4(l[0],l[1],l[2],l[3]);
    *(short4*)(Xl+i0+4) = make_short4(l[4],l[5],l[6],l[7]);
}

// ======================= bf16x3 MFMA GEMM: BM=128 BN=64, wave tile 64x32 =======================
// OUT_MODE: 0=fp32; 1=split bf16 (relu opt); 2=fp32 + split(relu(v)); 3=single bf16
template<int OUT_MODE, int RELU_OUT, int HAS_ADD>
__global__ __launch_bounds__(256) void gemm_mfma(
    const short* __restrict__ Ah, const short* __restrict__ Al,
    const short* __restrict__ Wh, const short* __restrict__ Wl,
    const float* __restrict__ bias, const float* __restrict__ addend,
    float* __restrict__ Cf, short* __restrict__ Ch, short* __restrict__ Cl)
{
    __shared__ short As_h[128*LDK], As_l[128*LDK];   // 10 KB each
    __shared__ short Bs_h[64*LDK],  Bs_l[64*LDK];    // 5 KB each
    const int t = threadIdx.x;
    const int row0 = blockIdx.y*128, col0 = blockIdx.x*64;
    const int lane = t & 63, w = t >> 6;
    const int m0 = (w>>1)*64, n0 = (w&1)*32;
    const int fl = lane & 15, quad = lane >> 4;
    const int a_row = t >> 1, a_k = (t & 1) * 16;
    const int b_row = t >> 2, b_k = (t & 3) * 8;

    f32x4 zero = {0.f,0.f,0.f,0.f};
    f32x4 acc[4][2];
    #pragma unroll
    for (int i=0;i<4;i++){ acc[i][0]=zero; acc[i][1]=zero; }

    for (int k0 = 0; k0 < 512; k0 += 32) {
        const size_t a_off = (size_t)(row0 + a_row)*512 + k0 + a_k;
        *(int4*)&As_h[a_row*LDK + a_k]     = *(const int4*)(Ah + a_off);
        *(int4*)&As_h[a_row*LDK + a_k + 8] = *(const int4*)(Ah + a_off + 8);
        *(int4*)&As_l[a_row*LDK + a_k]     = *(const int4*)(Al + a_off);
        *(int4*)&As_l[a_row*LDK + a_k + 8] = *(const int4*)(Al + a_off + 8);
        const size_t b_off = (size_t)(col0 + b_row)*512 + k0 + b_k;
        *(int4*)&Bs_h[b_row*LDK + b_k] = *(const int4*)(Wh + b_off);
        *(int4*)&Bs_l[b_row*LDK + b_k] = *(const int4*)(Wl + b_off);
        __syncthreads();

        bf16x8 fah[4], fal[4], fbh[2], fbl[2];
        #pragma unroll
        for (int i=0;i<4;i++) {
            fah[i] = *(const bf16x8*)&As_h[(m0 + i*16 + fl)*LDK + quad*8];
            fal[i] = *(const bf16x8*)&As_l[(m0 + i*16 + fl)*LDK + quad*8];
        }
        #pragma unroll
        for (int j=0;j<2;j++) {
            fbh[j] = *(const bf16x8*)&Bs_h[(n0 + j*16 + fl)*LDK + quad*8];
            fbl[j] = *(const bf16x8*)&Bs_l[(n0 + j*16 + fl)*LDK + quad*8];
        }
        #pragma unroll
        for (int i=0;i<4;i++)
        #pragma unroll
        for (int j=0;j<2;j++)
            acc[i][j] = __builtin_amdgcn_mfma_f32_16x16x32_bf16(fah[i], fbh[j], acc[i][j], 0,0,0);
        #pragma unroll
        for (int i=0;i<4;i++)
        #pragma unroll
        for (int j=0;j<2;j++)
            acc[i][j] = __builtin_amdgcn_mfma_f32_16x16x32_bf16(fah[i], fbl[j], acc[i][j], 0,0,0);
        #pragma unroll
        for (int i=0;i<4;i++)
        #pragma unroll
        for (int j=0;j<2;j++)
            acc[i][j] = __builtin_amdgcn_mfma_f32_16x16x32_bf16(fal[i], fbh[j], acc[i][j], 0,0,0);
        __syncthreads();
    }
    #pragma unroll
    for (int i=0;i<4;i++)
    #pragma unroll
    for (int j=0;j<2;j++) {
        const int col = col0 + n0 + j*16 + fl;
        const float bb = bias ? bias[col] : 0.f;
        #pragma unroll
        for (int r=0;r<4;r++) {
            const int row = row0 + m0 + i*16 + quad*4 + r;
            const size_t off = (size_t)row*512 + col;
            float v = acc[i][j][r] + bb;
            if (HAS_ADD) v += addend[off];
            if (OUT_MODE == 0) {
                if (RELU_OUT) v = fmaxf(v,0.f);
                Cf[off] = v;
            } else if (OUT_MODE == 1) {
                if (RELU_OUT) v = fmaxf(v,0.f);
                short h,l; split2(v,h,l); Ch[off]=h; Cl[off]=l;
            } else if (OUT_MODE == 2) {
                Cf[off] = v;
                short h,l; split2(fmaxf(v,0.f),h,l); Ch[off]=h; Cl[off]=l;
            } else {
                if (RELU_OUT) v = fmaxf(v,0.f);
                Ch[off] = (short)f2b(v);
            }
        }
    }
}

// ======================= builders (write pre-split A) =======================
__global__ __launch_bounds__(256) void build_apos_split(
    const float* __restrict__ xyz_q, const float* __restrict__ axyz, const int* __restrict__ knn,
    const float* __restrict__ d1w, const float* __restrict__ d1b,
    short* __restrict__ Ah, short* __restrict__ Al, int qbase)
{
    const int r = blockIdx.x;
    const int gr = qbase*8 + r;
    const int b  = gr >> 15;
    const int gq = gr >> 3;
    const int idx = knn[gr];
    const float* qp = xyz_q + (size_t)gq*3;
    const float* ap = axyz + (size_t)(b*NA + idx)*3;
    const float dx = qp[0]-ap[0], dy = qp[1]-ap[1], dz = qp[2]-ap[2];
    for (int c = threadIdx.x; c < 512; c += 256) {
        float v = fmaxf(fmaf(dx, d1w[c], fmaf(dy, d1w[512+c], fmaf(dz, d1w[1024+c], d1b[c]))), 0.f);
        short h,l; split2(v,h,l);
        Ah[(size_t)r*512 + c] = h; Al[(size_t)r*512 + c] = l;
    }
}

__global__ __launch_bounds__(256) void build_ag1_split(
    const float* __restrict__ q_attn, const float* __restrict__ kgv,
    const short* __restrict__ ak_bf, const short* __restrict__ pos_bf, const int* __restrict__ knn,
    short* __restrict__ Ah, short* __restrict__ Al, int qbase)
{
    const int r = blockIdx.x;
    const int q = r / 9, n = r - q*9;
    const int b = qbase >> 12;
    const float* qa = q_attn + b*512;
    if (n < 8) {
        const int aidx = knn[(size_t)(qbase + q)*8 + n];
        const short* kp = ak_bf + (size_t)(b*NA + aidx)*512;
        const short* pp = pos_bf + (size_t)(q*8 + n)*512;
        for (int c = threadIdx.x; c < 512; c += 256) {
            float v = qa[c] - b2f((unsigned short)kp[c]) + b2f((unsigned short)pp[c]);
            short h,l; split2(v,h,l);
            Ah[(size_t)r*512 + c] = h; Al[(size_t)r*512 + c] = l;
        }
    } else {
        const float* kp = kgv + b*512;
        for (int c = threadIdx.x; c < 512; c += 256) {
            float v = qa[c] - kp[c];
            short h,l; split2(v,h,l);
            Ah[(size_t)r*512 + c] = h; Al[(size_t)r*512 + c] = l;
        }
    }
}

// ======================= softmax + aggregation -> lat (split) =======================
__global__ __launch_bounds__(256) void softmax_agg(
    const float* __restrict__ attn_pre, const short* __restrict__ pos_bf,
    const float* __restrict__ av, const float* __restrict__ vgv,
    const int* __restrict__ knn, short* __restrict__ lath, short* __restrict__ latl, int qbase)
{
    __shared__ int sk[8];
    const int q = blockIdx.x;
    const int gq = qbase + q;
    const int b = qbase >> 12;
    const int t = threadIdx.x;
    if (t < 8) sk[t] = knn[(size_t)gq*8 + t];
    __syncthreads();
    for (int c = t; c < 512; c += 256) {
        float p[9];
        #pragma unroll
        for (int n=0;n<9;n++) p[n] = attn_pre[(size_t)(q*9+n)*512 + c];
        float m = p[0];
        #pragma unroll
        for (int n=1;n<9;n++) m = fmaxf(m, p[n]);
        float e[9], s = 0.f;
        #pragma unroll
        for (int n=0;n<9;n++){ e[n] = expf(p[n]-m); s += e[n]; }
        const float inv = 1.0f / s;
        float acc = 0.f;
        #pragma unroll
        for (int n=0;n<8;n++) {
            float vv = av[(size_t)(b*NA + sk[n])*512 + c] + b2f((unsigned short)pos_bf[(size_t)(q*8+n)*512 + c]);
            acc = fmaf(e[n]*inv, vv, acc);
        }
        acc = fmaf(e[8]*inv, vgv[b*512 + c], acc);
        short h,l; split2(acc,h,l);
        lath[(size_t)gq*512 + c] = h; latl[(size_t)gq*512 + c] = l;
    }
}

// ======================= PE + first decoder layer =======================
__global__ __launch_bounds__(256) void pe_fc(
    const float* __restrict__ xyz_q, const float* __restrict__ fw, const float* __restrict__ fb,
    float* __restrict__ net)
{
    __shared__ float spe[16*60];
    const int t = threadIdx.x;
    const int q0 = blockIdx.x * 16;
    for (int i=t;i<960;i+=256) {
        int ql = i/60, j = i - ql*60;
        int l = j/6; int r6 = j - l*6; int s = r6/3; int d = r6 - s*3;
        float pv = xyz_q[(size_t)(q0+ql)*3 + d];
        float a = pv * (3.14159265358979323846f * (float)(1<<l));
        spe[ql*60+j] = (s==0) ? sinf(a) : cosf(a);
    }
    __syncthreads();
    float acc0[16], acc1[16];
    #pragma unroll
    for (int ql=0;ql<16;ql++){ acc0[ql]=0.f; acc1[ql]=0.f; }
    const int c0 = t, c1 = t + 256;
    for (int k=0;k<60;k++) {
        float w0 = fw[k*512 + c0];
        float w1 = fw[k*512 + c1];
        #pragma unroll
        for (int ql=0;ql<16;ql++) {
            float pv = spe[ql*60+k];
            acc0[ql] = fmaf(pv, w0, acc0[ql]);
            acc1[ql] = fmaf(pv, w1, acc1[ql]);
        }
    }
    const float b0v = fb[c0], b1v = fb[c1];
    #pragma unroll
    for (int ql=0;ql<16;ql++) {
        net[(size_t)(q0+ql)*512 + c0] = acc0[ql] + b0v;
        net[(size_t)(q0+ql)*512 + c1] = acc1[ql] + b1v;
    }
}

// ======================= launch =======================
extern "C" void kernel_launch(void* const* d_in, const int* in_sizes, int n_in,
                              void* d_out, int out_size, void* d_ws, size_t ws_size,
                              hipStream_t stream) {
    const float* xyz_q  = (const float*)d_in[0];
    const float* gf     = (const float*)d_in[1];
    const float* axyz   = (const float*)d_in[2];
    const float* afeat  = (const float*)d_in[3];
    const float* w_qs   = (const float*)d_in[4];
    const float* w_ks   = (const float*)d_in[5];
    const float* w_vs   = (const float*)d_in[6];
    const float* w_kg   = (const float*)d_in[7];
    const float* w_vg   = (const float*)d_in[8];
    const float* d1_w   = (const float*)d_in[9];
    const float* d1_b   = (const float*)d_in[10];
    const float* d2_w   = (const float*)d_in[11];
    const float* d2_b   = (const float*)d_in[12];
    const float* g1_w   = (const float*)d_in[13];
    const float* g1_b   = (const float*)d_in[14];
    const float* g2_w   = (const float*)d_in[15];
    const float* g2_b   = (const float*)d_in[16];
    const float* fc_p_w = (const float*)d_in[17];
    const float* fc_p_b = (const float*)d_in[18];
    const float* fc_c_w = (const float*)d_in[19];
    const float* fc_c_b = (const float*)d_in[20];
    const float* blk0_w = (const float*)d_in[21];
    const float* blk0_b = (const float*)d_in[22];
    const float* blk1_w = (const float*)d_in[23];
    const float* blk1_b = (const float*)d_in[24];
    float* out = (float*)d_out;

    const size_t MB = 1u<<20;
    char* base = (char*)d_ws;
    // ---- persistent (21 MB) ----
    float* q_attn = (float*)base;
    float* kgv    = q_attn + 1024;
    float* vgv    = kgv + 1024;
    int*   knn    = (int*)(base + 16*1024);
    short* wd2h = (short*)(base + 1*MB); short* wd2l = wd2h + 262144;
    short* wg1h = wd2l + 262144;         short* wg1l = wg1h + 262144;
    short* wg2h = wg1l + 262144;         short* wg2l = wg2h + 262144;
    short* wth  = wg2l + 262144;         short* wtl  = wth  + 262144;
    short* lath = (short*)(base + 5*MB);
    short* latl = (short*)(base + 13*MB);
    // ---- transient (34 MB): total 55 MB ----
    char* T = base + 21*MB;
    short* ak_bf = (short*)T;
    float* av_f  = (float*)(T + 4*MB);
    char* R1 = T + 12*MB;
    char* R2 = T + 21*MB;
    char* R3 = T + 30*MB;
    short* afh = (short*)R1; short* afl = (short*)(R1 + 4*MB);
    short* aposh = (short*)R2; short* aposl = (short*)(R2 + 4*MB);
    short* posb  = (short*)R3;
    short* ag1h = (short*)R1; short* ag1l = (short*)(R1 + 4718592);
    short* yh   = (short*)R2; short* yl   = (short*)(R2 + 4718592);
    float* attn_pre = (float*)R1;
    short* nrh = (short*)T;            short* nrl = (short*)(T + 8*MB);
    short* hdh = (short*)(T + 16*MB);  short* hdl = (short*)(T + 24*MB);
    if ((size_t)(55*MB) > ws_size) return;

    proj_small<<<dim3(6), dim3(256), 0, stream>>>(gf, w_qs, w_kg, w_vg, q_attn, kgv, vgv);
    knn_kernel<<<dim3(256), dim3(256), 0, stream>>>(xyz_q, axyz, knn);

    split_fp32<<<dim3(1024), dim3(256), 0, stream>>>(afeat, afh, afl);
    prep_w<<<dim3(128), dim3(256), 0, stream>>>(w_ks, wth, wtl);
    gemm_mfma<3,0,0><<<dim3(8,32), dim3(256), 0, stream>>>(afh, afl, wth, wtl, nullptr, nullptr, nullptr, ak_bf, nullptr);
    prep_w<<<dim3(128), dim3(256), 0, stream>>>(w_vs, wth, wtl);
    gemm_mfma<0,0,0><<<dim3(8,32), dim3(256), 0, stream>>>(afh, afl, wth, wtl, nullptr, nullptr, av_f, nullptr, nullptr);

    prep_w<<<dim3(128), dim3(256), 0, stream>>>(d2_w, wd2h, wd2l);
    prep_w<<<dim3(128), dim3(256), 0, stream>>>(g1_w, wg1h, wg1l);
    prep_w<<<dim3(128), dim3(256), 0, stream>>>(g2_w, wg2h, wg2l);

    for (int qbase = 0; qbase < B*NQ; qbase += CH) {
        build_apos_split<<<dim3(CH*8), dim3(256), 0, stream>>>(xyz_q, axyz, knn, d1_w, d1_b, aposh, aposl, qbase);
        gemm_mfma<3,0,0><<<dim3(8, 32), dim3(256), 0, stream>>>(aposh, aposl, wd2h, wd2l, d2_b, nullptr, nullptr, posb, nullptr);
        build_ag1_split<<<dim3(CH*9), dim3(256), 0, stream>>>(q_attn, kgv, ak_bf, posb, knn, ag1h, ag1l, qbase);
        gemm_mfma<1,1,0><<<dim3(8, 36), dim3(256), 0, stream>>>(ag1h, ag1l, wg1h, wg1l, g1_b, nullptr, nullptr, yh, yl);
        gemm_mfma<0,0,0><<<dim3(8, 36), dim3(256), 0, stream>>>(yh, yl, wg2h, wg2l, g2_b, nullptr, attn_pre, nullptr, nullptr);
        softmax_agg<<<dim3(CH), dim3(256), 0, stream>>>(attn_pre, posb, av_f, vgv, knn, lath, latl, qbase);
    }

    pe_fc<<<dim3(512), dim3(256), 0, stream>>>(xyz_q, fc_p_w, fc_p_b, out);
    for (int i=0;i<5;i++) {
        const float* cw  = fc_c_w + (size_t)i*512*512;
        const float* cb  = fc_c_b + (size_t)i*512;
        const float* b0w = blk0_w + (size_t)i*512*512;
        const float* b0b = blk0_b + (size_t)i*512;
        const float* b1w = blk1_w + (size_t)i*512*512;
        const float* b1b = blk1_b + (size_t)i*512;
        prep_w<<<dim3(128), dim3(256), 0, stream>>>(cw, wth, wtl);
        gemm_mfma<2,0,1><<<dim3(8,64), dim3(256), 0, stream>>>(lath, latl, wth, wtl, cb, out, out, nrh, nrl);
        prep_w<<<dim3(128), dim3(256), 0, stream>>>(b0w, wth, wtl);
        gemm_mfma<1,1,0><<<dim3(8,64), dim3(256), 0, stream>>>(nrh, nrl, wth, wtl, b0b, nullptr, nullptr, hdh, hdl);
        prep_w<<<dim3(128), dim3(256), 0, stream>>>(b1w, wth, wtl);
        gemm_mfma<0,0,1><<<dim3(8,64), dim3(256), 0, stream>>>(hdh, hdl, wth, wtl, b1b, out, out, nullptr, nullptr);
    }
}

// Round 9
// 1836.388 us; speedup vs baseline: 1.2899x; 1.2899x over previous
//
#include <hip/hip_runtime.h>

#define B 2
#define NQ 4096
#define NA 2048
#define CH 512   // attention chunk (16 chunks)
#define LDK 40   // LDS row stride (shorts) — conflict-free-ish (2-way)

typedef __attribute__((ext_vector_type(8))) short bf16x8;
typedef __attribute__((ext_vector_type(4))) float f32x4;

__device__ __forceinline__ float b2f(unsigned short u){ union{unsigned i; float f;} c; c.i=((unsigned)u)<<16; return c.f; }
__device__ __forceinline__ unsigned short f2b(float f){ union{float f; unsigned u;} c; c.f=f; unsigned u=c.u; u += 0x7FFFu + ((u>>16)&1u); return (unsigned short)(u>>16); }
__device__ __forceinline__ void split2(float x, short& h, short& l){
    unsigned short hh = f2b(x); h = (short)hh; l = (short)f2b(x - b2f(hh));
}

// ======================= small projections =======================
__global__ __launch_bounds__(256) void proj_small(
    const float* __restrict__ gf,
    const float* __restrict__ w_qs, const float* __restrict__ w_kg, const float* __restrict__ w_vg,
    float* __restrict__ q_attn, float* __restrict__ kgv, float* __restrict__ vgv)
{
    int mat = blockIdx.x >> 1, b = blockIdx.x & 1;
    const float* W = (mat==0) ? w_qs : (mat==1 ? w_kg : w_vg);
    float* O       = (mat==0) ? q_attn : (mat==1 ? kgv : vgv);
    __shared__ float sg[512];
    int t = threadIdx.x;
    for (int i=t;i<512;i+=256) sg[i] = gf[b*512+i];
    __syncthreads();
    for (int c=t;c<512;c+=256) {
        float acc = 0.f;
        for (int k=0;k<512;k++) acc = fmaf(sg[k], W[k*512+c], acc);
        O[b*512+c] = acc;
    }
}

// ======================= KNN: 512 blocks, 16 thr/query, f64 exact =======================
__global__ __launch_bounds__(256) void knn_kernel(
    const float* __restrict__ xyz_q, const float* __restrict__ axyz, int* __restrict__ knn)
{
    __shared__ float4 sa[NA];           // 32 KB
    __shared__ double cd[16*129];       // 16 q x 128 cands, +1 pad
    __shared__ int    ci[16*129];
    const int t = threadIdx.x;
    const int b  = blockIdx.x >> 8;                      // 256 blocks/batch
    const int qi = t >> 4;                               // 0..15
    const int q  = ((blockIdx.x & 255) << 4) + qi;
    const int g  = t & 15;                               // 16 threads/query
    for (int i=t;i<NA;i+=256) {
        const float* ap = axyz + (size_t)(b*NA+i)*3;
        sa[i] = make_float4(ap[0],ap[1],ap[2],0.f);
    }
    __syncthreads();
    const double qx = (double)xyz_q[(size_t)(b*NQ+q)*3+0];
    const double qy = (double)xyz_q[(size_t)(b*NQ+q)*3+1];
    const double qz = (double)xyz_q[(size_t)(b*NQ+q)*3+2];
    const double qq = (qx*qx + qy*qy) + qz*qz;
    double best[8]; int bid[8];
    #pragma unroll
    for (int j=0;j<8;j++){ best[j]=1.0e300; bid[j]=0; }
    for (int jj=0; jj<128; jj++) {
        const int i = jj*16 + g;        // interleaved: conflict-free + broadcast
        float4 a = sa[i];
        double ax=(double)a.x, ay=(double)a.y, az=(double)a.z;
        double aa  = (ax*ax + ay*ay) + az*az;
        double dot = (qx*ax + qy*ay) + qz*az;
        double dd  = (qq + aa) - 2.0*dot;
        if (dd < best[7]) {
            best[7]=dd; bid[7]=i;
            #pragma unroll
            for (int j=7;j>0;--j) if (best[j] < best[j-1]) {
                double tf=best[j]; best[j]=best[j-1]; best[j-1]=tf;
                int ti=bid[j]; bid[j]=bid[j-1]; bid[j-1]=ti;
            }
        }
    }
    const int cbase = qi*129 + g*8;
    #pragma unroll
    for (int j=0;j<8;j++){ cd[cbase+j]=best[j]; ci[cbase+j]=bid[j]; }
    __syncthreads();
    if (g==0) {
        double fb[8]; int fi[8];
        #pragma unroll
        for (int j=0;j<8;j++){ fb[j]=1.0e300; fi[j]=0; }
        const int c0 = qi*129;
        for (int c=c0; c<c0+128; c++) {
            double d = cd[c];
            if (d < fb[7]) {
                fb[7]=d; fi[7]=ci[c];
                #pragma unroll
                for (int j=7;j>0;--j) if (fb[j] < fb[j-1]) {
                    double tf=fb[j]; fb[j]=fb[j-1]; fb[j-1]=tf;
                    int ti=fi[j]; fi[j]=fi[j-1]; fi[j-1]=ti;
                }
            }
        }
        #pragma unroll
        for (int j=0;j<8;j++) knn[(size_t)(b*NQ+q)*8+j] = fi[j];
    }
}

// ======================= weight prep: W[k][n] fp32 -> [n][k] hi/lo bf16 =======================
__global__ __launch_bounds__(256) void prep_w(
    const float* __restrict__ W, short* __restrict__ Wh, short* __restrict__ Wl)
{
    const int gid = blockIdx.x*256 + threadIdx.x;
    const int n  = gid & 511;
    const int kc = (gid >> 9) * 8;
    short hi[8], lo[8];
    #pragma unroll
    for (int j=0;j<8;j++) split2(W[(size_t)(kc+j)*512 + n], hi[j], lo[j]);
    *(short4*)&Wh[(size_t)n*512 + kc]     = make_short4(hi[0],hi[1],hi[2],hi[3]);
    *(short4*)&Wh[(size_t)n*512 + kc + 4] = make_short4(hi[4],hi[5],hi[6],hi[7]);
    *(short4*)&Wl[(size_t)n*512 + kc]     = make_short4(lo[0],lo[1],lo[2],lo[3]);
    *(short4*)&Wl[(size_t)n*512 + kc + 4] = make_short4(lo[4],lo[5],lo[6],lo[7]);
}

// ======================= activation split: fp32 -> hi/lo bf16 =======================
__global__ __launch_bounds__(256) void split_fp32(
    const float* __restrict__ X, short* __restrict__ Xh, short* __restrict__ Xl)
{
    const size_t i0 = ((size_t)blockIdx.x*256 + threadIdx.x)*8;
    float4 a = *(const float4*)(X+i0), bq = *(const float4*)(X+i0+4);
    float v[8] = {a.x,a.y,a.z,a.w,bq.x,bq.y,bq.z,bq.w};
    short h[8], l[8];
    #pragma unroll
    for (int j=0;j<8;j++) split2(v[j], h[j], l[j]);
    *(short4*)(Xh+i0)   = make_short4(h[0],h[1],h[2],h[3]);
    *(short4*)(Xh+i0+4) = make_short4(h[4],h[5],h[6],h[7]);
    *(short4*)(Xl+i0)   = make_short4(l[0],l[1],l[2],l[3]);
    *(short4*)(Xl+i0+4) = make_short4(l[4],l[5],l[6],l[7]);
}

// ======================= x3 MFMA GEMM (A hi/lo): 64x64 block, 32x32 wave =======================
// OUT_MODE: 0=fp32; 1=split bf16; 2=fp32 + split(relu(v)); 3=single bf16
template<int OUT_MODE, int RELU_OUT, int HAS_ADD>
__global__ __launch_bounds__(256) void gemm3(
    const short* __restrict__ Ah, const short* __restrict__ Al,
    const short* __restrict__ Wh, const short* __restrict__ Wl,
    const float* __restrict__ bias, const float* __restrict__ addend,
    float* __restrict__ Cf, short* __restrict__ Ch, short* __restrict__ Cl)
{
    __shared__ short As_h[64*LDK], As_l[64*LDK], Bs_h[64*LDK], Bs_l[64*LDK];
    const int t = threadIdx.x;
    const int row0 = blockIdx.y*64, col0 = blockIdx.x*64;
    const int lane = t & 63, w = t >> 6;
    const int m0 = (w>>1)*32, n0 = (w&1)*32;
    const int fl = lane & 15, quad = lane >> 4;
    const int s_row = t >> 2, s_k = (t & 3) * 8;

    f32x4 zero = {0.f,0.f,0.f,0.f};
    f32x4 acc[2][2];
    acc[0][0]=zero; acc[0][1]=zero; acc[1][0]=zero; acc[1][1]=zero;

    for (int k0 = 0; k0 < 512; k0 += 32) {
        *(int4*)&As_h[s_row*LDK + s_k] = *(const int4*)(Ah + (size_t)(row0+s_row)*512 + k0 + s_k);
        *(int4*)&As_l[s_row*LDK + s_k] = *(const int4*)(Al + (size_t)(row0+s_row)*512 + k0 + s_k);
        *(int4*)&Bs_h[s_row*LDK + s_k] = *(const int4*)(Wh + (size_t)(col0+s_row)*512 + k0 + s_k);
        *(int4*)&Bs_l[s_row*LDK + s_k] = *(const int4*)(Wl + (size_t)(col0+s_row)*512 + k0 + s_k);
        __syncthreads();
        bf16x8 fah[2], fal[2], fbh[2], fbl[2];
        #pragma unroll
        for (int i=0;i<2;i++) {
            fah[i] = *(const bf16x8*)&As_h[(m0 + i*16 + fl)*LDK + quad*8];
            fal[i] = *(const bf16x8*)&As_l[(m0 + i*16 + fl)*LDK + quad*8];
            fbh[i] = *(const bf16x8*)&Bs_h[(n0 + i*16 + fl)*LDK + quad*8];
            fbl[i] = *(const bf16x8*)&Bs_l[(n0 + i*16 + fl)*LDK + quad*8];
        }
        #pragma unroll
        for (int i=0;i<2;i++)
        #pragma unroll
        for (int j=0;j<2;j++)
            acc[i][j] = __builtin_amdgcn_mfma_f32_16x16x32_bf16(fah[i], fbh[j], acc[i][j], 0,0,0);
        #pragma unroll
        for (int i=0;i<2;i++)
        #pragma unroll
        for (int j=0;j<2;j++)
            acc[i][j] = __builtin_amdgcn_mfma_f32_16x16x32_bf16(fah[i], fbl[j], acc[i][j], 0,0,0);
        #pragma unroll
        for (int i=0;i<2;i++)
        #pragma unroll
        for (int j=0;j<2;j++)
            acc[i][j] = __builtin_amdgcn_mfma_f32_16x16x32_bf16(fal[i], fbh[j], acc[i][j], 0,0,0);
        __syncthreads();
    }
    #pragma unroll
    for (int i=0;i<2;i++)
    #pragma unroll
    for (int j=0;j<2;j++) {
        const int col = col0 + n0 + j*16 + fl;
        const float bb = bias ? bias[col] : 0.f;
        #pragma unroll
        for (int r=0;r<4;r++) {
            const int row = row0 + m0 + i*16 + quad*4 + r;
            const size_t off = (size_t)row*512 + col;
            float v = acc[i][j][r] + bb;
            if (HAS_ADD) v += addend[off];
            if (OUT_MODE == 0) {
                if (RELU_OUT) v = fmaxf(v,0.f);
                Cf[off] = v;
            } else if (OUT_MODE == 1) {
                if (RELU_OUT) v = fmaxf(v,0.f);
                short h,l; split2(v,h,l); Ch[off]=h; Cl[off]=l;
            } else if (OUT_MODE == 2) {
                Cf[off] = v;
                short h,l; split2(fmaxf(v,0.f),h,l); Ch[off]=h; Cl[off]=l;
            } else {
                if (RELU_OUT) v = fmaxf(v,0.f);
                Ch[off] = (short)f2b(v);
            }
        }
    }
}

// ======================= x2 MFMA GEMM (A single bf16, B hi/lo) =======================
// OUT_MODE: 0=fp32; 3=single bf16
template<int OUT_MODE, int RELU_OUT>
__global__ __launch_bounds__(256) void gemm2(
    const short* __restrict__ Ab,
    const short* __restrict__ Wh, const short* __restrict__ Wl,
    const float* __restrict__ bias,
    float* __restrict__ Cf, short* __restrict__ Cb)
{
    __shared__ short As[64*LDK], Bs_h[64*LDK], Bs_l[64*LDK];
    const int t = threadIdx.x;
    const int row0 = blockIdx.y*64, col0 = blockIdx.x*64;
    const int lane = t & 63, w = t >> 6;
    const int m0 = (w>>1)*32, n0 = (w&1)*32;
    const int fl = lane & 15, quad = lane >> 4;
    const int s_row = t >> 2, s_k = (t & 3) * 8;

    f32x4 zero = {0.f,0.f,0.f,0.f};
    f32x4 acc[2][2];
    acc[0][0]=zero; acc[0][1]=zero; acc[1][0]=zero; acc[1][1]=zero;

    for (int k0 = 0; k0 < 512; k0 += 32) {
        *(int4*)&As[s_row*LDK + s_k]   = *(const int4*)(Ab + (size_t)(row0+s_row)*512 + k0 + s_k);
        *(int4*)&Bs_h[s_row*LDK + s_k] = *(const int4*)(Wh + (size_t)(col0+s_row)*512 + k0 + s_k);
        *(int4*)&Bs_l[s_row*LDK + s_k] = *(const int4*)(Wl + (size_t)(col0+s_row)*512 + k0 + s_k);
        __syncthreads();
        bf16x8 fa[2], fbh[2], fbl[2];
        #pragma unroll
        for (int i=0;i<2;i++) {
            fa[i]  = *(const bf16x8*)&As[(m0 + i*16 + fl)*LDK + quad*8];
            fbh[i] = *(const bf16x8*)&Bs_h[(n0 + i*16 + fl)*LDK + quad*8];
            fbl[i] = *(const bf16x8*)&Bs_l[(n0 + i*16 + fl)*LDK + quad*8];
        }
        #pragma unroll
        for (int i=0;i<2;i++)
        #pragma unroll
        for (int j=0;j<2;j++)
            acc[i][j] = __builtin_amdgcn_mfma_f32_16x16x32_bf16(fa[i], fbh[j], acc[i][j], 0,0,0);
        #pragma unroll
        for (int i=0;i<2;i++)
        #pragma unroll
        for (int j=0;j<2;j++)
            acc[i][j] = __builtin_amdgcn_mfma_f32_16x16x32_bf16(fa[i], fbl[j], acc[i][j], 0,0,0);
        __syncthreads();
    }
    #pragma unroll
    for (int i=0;i<2;i++)
    #pragma unroll
    for (int j=0;j<2;j++) {
        const int col = col0 + n0 + j*16 + fl;
        const float bb = bias ? bias[col] : 0.f;
        #pragma unroll
        for (int r=0;r<4;r++) {
            const int row = row0 + m0 + i*16 + quad*4 + r;
            const size_t off = (size_t)row*512 + col;
            float v = acc[i][j][r] + bb;
            if (RELU_OUT) v = fmaxf(v,0.f);
            if (OUT_MODE == 0) Cf[off] = v;
            else               Cb[off] = (short)f2b(v);
        }
    }
}

// ======================= builders (single bf16 A) =======================
__global__ __launch_bounds__(256) void build_apos_bf(
    const float* __restrict__ xyz_q, const float* __restrict__ axyz, const int* __restrict__ knn,
    const float* __restrict__ d1w, const float* __restrict__ d1b,
    short* __restrict__ Ab, int qbase)
{
    const int r = blockIdx.x;
    const int gr = qbase*8 + r;
    const int b  = gr >> 15;
    const int gq = gr >> 3;
    const int idx = knn[gr];
    const float* qp = xyz_q + (size_t)gq*3;
    const float* ap = axyz + (size_t)(b*NA + idx)*3;
    const float dx = qp[0]-ap[0], dy = qp[1]-ap[1], dz = qp[2]-ap[2];
    for (int c = threadIdx.x; c < 512; c += 256) {
        float v = fmaxf(fmaf(dx, d1w[c], fmaf(dy, d1w[512+c], fmaf(dz, d1w[1024+c], d1b[c]))), 0.f);
        Ab[(size_t)r*512 + c] = (short)f2b(v);
    }
}

__global__ __launch_bounds__(256) void build_ag1_bf(
    const float* __restrict__ q_attn, const float* __restrict__ kgv,
    const short* __restrict__ ak_bf, const short* __restrict__ pos_bf, const int* __restrict__ knn,
    short* __restrict__ Ab, int qbase)
{
    const int r = blockIdx.x;
    const int q = r / 9, n = r - q*9;
    const int b = qbase >> 12;
    const float* qa = q_attn + b*512;
    if (n < 8) {
        const int aidx = knn[(size_t)(qbase + q)*8 + n];
        const short* kp = ak_bf + (size_t)(b*NA + aidx)*512;
        const short* pp = pos_bf + (size_t)(q*8 + n)*512;
        for (int c = threadIdx.x; c < 512; c += 256) {
            float v = qa[c] - b2f((unsigned short)kp[c]) + b2f((unsigned short)pp[c]);
            Ab[(size_t)r*512 + c] = (short)f2b(v);
        }
    } else {
        const float* kp = kgv + b*512;
        for (int c = threadIdx.x; c < 512; c += 256) {
            float v = qa[c] - kp[c];
            Ab[(size_t)r*512 + c] = (short)f2b(v);
        }
    }
}

// ======================= softmax + aggregation -> lat (split hi/lo) =======================
__global__ __launch_bounds__(256) void softmax_agg(
    const float* __restrict__ attn_pre, const short* __restrict__ pos_bf,
    const short* __restrict__ av_bf, const float* __restrict__ vgv,
    const int* __restrict__ knn, short* __restrict__ lath, short* __restrict__ latl, int qbase)
{
    __shared__ int sk[8];
    const int q = blockIdx.x;
    const int gq = qbase + q;
    const int b = qbase >> 12;
    const int t = threadIdx.x;
    if (t < 8) sk[t] = knn[(size_t)gq*8 + t];
    __syncthreads();
    for (int c = t; c < 512; c += 256) {
        float p[9];
        #pragma unroll
        for (int n=0;n<9;n++) p[n] = attn_pre[(size_t)(q*9+n)*512 + c];
        float m = p[0];
        #pragma unroll
        for (int n=1;n<9;n++) m = fmaxf(m, p[n]);
        float e[9], s = 0.f;
        #pragma unroll
        for (int n=0;n<9;n++){ e[n] = expf(p[n]-m); s += e[n]; }
        const float inv = 1.0f / s;
        float acc = 0.f;
        #pragma unroll
        for (int n=0;n<8;n++) {
            float vv = b2f((unsigned short)av_bf[(size_t)(b*NA + sk[n])*512 + c])
                     + b2f((unsigned short)pos_bf[(size_t)(q*8+n)*512 + c]);
            acc = fmaf(e[n]*inv, vv, acc);
        }
        acc = fmaf(e[8]*inv, vgv[b*512 + c], acc);
        short h,l; split2(acc,h,l);
        lath[(size_t)gq*512 + c] = h; latl[(size_t)gq*512 + c] = l;
    }
}

// ======================= PE + first decoder layer =======================
__global__ __launch_bounds__(256) void pe_fc(
    const float* __restrict__ xyz_q, const float* __restrict__ fw, const float* __restrict__ fb,
    float* __restrict__ net)
{
    __shared__ float spe[16*60];
    const int t = threadIdx.x;
    const int q0 = blockIdx.x * 16;
    for (int i=t;i<960;i+=256) {
        int ql = i/60, j = i - ql*60;
        int l = j/6; int r6 = j - l*6; int s = r6/3; int d = r6 - s*3;
        float pv = xyz_q[(size_t)(q0+ql)*3 + d];
        float a = pv * (3.14159265358979323846f * (float)(1<<l));
        spe[ql*60+j] = (s==0) ? sinf(a) : cosf(a);
    }
    __syncthreads();
    float acc0[16], acc1[16];
    #pragma unroll
    for (int ql=0;ql<16;ql++){ acc0[ql]=0.f; acc1[ql]=0.f; }
    const int c0 = t, c1 = t + 256;
    for (int k=0;k<60;k++) {
        float w0 = fw[k*512 + c0];
        float w1 = fw[k*512 + c1];
        #pragma unroll
        for (int ql=0;ql<16;ql++) {
            float pv = spe[ql*60+k];
            acc0[ql] = fmaf(pv, w0, acc0[ql]);
            acc1[ql] = fmaf(pv, w1, acc1[ql]);
        }
    }
    const float b0v = fb[c0], b1v = fb[c1];
    #pragma unroll
    for (int ql=0;ql<16;ql++) {
        net[(size_t)(q0+ql)*512 + c0] = acc0[ql] + b0v;
        net[(size_t)(q0+ql)*512 + c1] = acc1[ql] + b1v;
    }
}

// ======================= launch =======================
extern "C" void kernel_launch(void* const* d_in, const int* in_sizes, int n_in,
                              void* d_out, int out_size, void* d_ws, size_t ws_size,
                              hipStream_t stream) {
    const float* xyz_q  = (const float*)d_in[0];
    const float* gf     = (const float*)d_in[1];
    const float* axyz   = (const float*)d_in[2];
    const float* afeat  = (const float*)d_in[3];
    const float* w_qs   = (const float*)d_in[4];
    const float* w_ks   = (const float*)d_in[5];
    const float* w_vs   = (const float*)d_in[6];
    const float* w_kg   = (const float*)d_in[7];
    const float* w_vg   = (const float*)d_in[8];
    const float* d1_w   = (const float*)d_in[9];
    const float* d1_b   = (const float*)d_in[10];
    const float* d2_w   = (const float*)d_in[11];
    const float* d2_b   = (const float*)d_in[12];
    const float* g1_w   = (const float*)d_in[13];
    const float* g1_b   = (const float*)d_in[14];
    const float* g2_w   = (const float*)d_in[15];
    const float* g2_b   = (const float*)d_in[16];
    const float* fc_p_w = (const float*)d_in[17];
    const float* fc_p_b = (const float*)d_in[18];
    const float* fc_c_w = (const float*)d_in[19];
    const float* fc_c_b = (const float*)d_in[20];
    const float* blk0_w = (const float*)d_in[21];
    const float* blk0_b = (const float*)d_in[22];
    const float* blk1_w = (const float*)d_in[23];
    const float* blk1_b = (const float*)d_in[24];
    float* out = (float*)d_out;

    const size_t MB = 1u<<20;
    char* base = (char*)d_ws;
    // ---- persistent (21 MB) ----
    float* q_attn = (float*)base;
    float* kgv    = q_attn + 1024;
    float* vgv    = kgv + 1024;
    int*   knn    = (int*)(base + 16*1024);
    short* wd2h = (short*)(base + 1*MB); short* wd2l = wd2h + 262144;
    short* wg1h = wd2l + 262144;         short* wg1l = wg1h + 262144;
    short* wg2h = wg1l + 262144;         short* wg2l = wg2h + 262144;
    short* wth  = wg2l + 262144;         short* wtl  = wth  + 262144;
    short* lath = (short*)(base + 5*MB);
    short* latl = (short*)(base + 13*MB);
    // ---- transient (32 MB): total 53 MB ----
    char* T = base + 21*MB;
    short* ak_bf = (short*)T;                  // 4 MB
    short* av_bf = (short*)(T + 4*MB);         // 4 MB
    char* R1 = T + 8*MB;                       // 10 MB
    char* R2 = T + 18*MB;                      // 8 MB
    char* R3 = T + 26*MB;                      // 4 MB (ends T+30)
    short* afh  = (short*)R1;                  // 8 MB (phase A)
    short* afl  = (short*)R2;                  // 8 MB (phase A)
    short* aposb = (short*)R2;                 // 4 MB (chunk)
    short* posb  = (short*)R3;                 // 4 MB (chunk)
    short* ag1b  = (short*)R1;                 // 4.72 MB (chunk)
    short* yb    = (short*)R2;                 // 4.72 MB (chunk, overlays dead aposb)
    float* attn_pre = (float*)R1;              // 9.44 MB (chunk, overlays dead ag1b)
    short* nrh = (short*)T;            short* nrl = (short*)(T + 8*MB);
    short* hdh = (short*)(T + 16*MB);  short* hdl = (short*)(T + 24*MB);  // ends T+32
    if ((size_t)(53*MB) > ws_size) return;

    proj_small<<<dim3(6), dim3(256), 0, stream>>>(gf, w_qs, w_kg, w_vg, q_attn, kgv, vgv);
    knn_kernel<<<dim3(512), dim3(256), 0, stream>>>(xyz_q, axyz, knn);

    split_fp32<<<dim3(1024), dim3(256), 0, stream>>>(afeat, afh, afl);
    prep_w<<<dim3(128), dim3(256), 0, stream>>>(w_ks, wth, wtl);
    gemm3<3,0,0><<<dim3(8,64), dim3(256), 0, stream>>>(afh, afl, wth, wtl, nullptr, nullptr, nullptr, ak_bf, nullptr);
    prep_w<<<dim3(128), dim3(256), 0, stream>>>(w_vs, wth, wtl);
    gemm3<3,0,0><<<dim3(8,64), dim3(256), 0, stream>>>(afh, afl, wth, wtl, nullptr, nullptr, nullptr, av_bf, nullptr);

    prep_w<<<dim3(128), dim3(256), 0, stream>>>(d2_w, wd2h, wd2l);
    prep_w<<<dim3(128), dim3(256), 0, stream>>>(g1_w, wg1h, wg1l);
    prep_w<<<dim3(128), dim3(256), 0, stream>>>(g2_w, wg2h, wg2l);

    for (int qbase = 0; qbase < B*NQ; qbase += CH) {
        build_apos_bf<<<dim3(CH*8), dim3(256), 0, stream>>>(xyz_q, axyz, knn, d1_w, d1_b, aposb, qbase);
        gemm2<3,0><<<dim3(8, CH*8/64), dim3(256), 0, stream>>>(aposb, wd2h, wd2l, d2_b, nullptr, posb);
        build_ag1_bf<<<dim3(CH*9), dim3(256), 0, stream>>>(q_attn, kgv, ak_bf, posb, knn, ag1b, qbase);
        gemm2<3,1><<<dim3(8, CH*9/64), dim3(256), 0, stream>>>(ag1b, wg1h, wg1l, g1_b, nullptr, yb);
        gemm2<0,0><<<dim3(8, CH*9/64), dim3(256), 0, stream>>>(yb, wg2h, wg2l, g2_b, attn_pre, nullptr);
        softmax_agg<<<dim3(CH), dim3(256), 0, stream>>>(attn_pre, posb, av_bf, vgv, knn, lath, latl, qbase);
    }

    pe_fc<<<dim3(512), dim3(256), 0, stream>>>(xyz_q, fc_p_w, fc_p_b, out);
    for (int i=0;i<5;i++) {
        const float* cw  = fc_c_w + (size_t)i*512*512;
        const float* cb  = fc_c_b + (size_t)i*512;
        const float* b0w = blk0_w + (size_t)i*512*512;
        const float* b0b = blk0_b + (size_t)i*512;
        const float* b1w = blk1_w + (size_t)i*512*512;
        const float* b1b = blk1_b + (size_t)i*512;
        prep_w<<<dim3(128), dim3(256), 0, stream>>>(cw, wth, wtl);
        gemm3<2,0,1><<<dim3(8,128), dim3(256), 0, stream>>>(lath, latl, wth, wtl, cb, out, out, nrh, nrl);
        prep_w<<<dim3(128), dim3(256), 0, stream>>>(b0w, wth, wtl);
        gemm3<1,1,0><<<dim3(8,128), dim3(256), 0, stream>>>(nrh, nrl, wth, wtl, b0b, nullptr, nullptr, hdh, hdl);
        prep_w<<<dim3(128), dim3(256), 0, stream>>>(b1w, wth, wtl);
        gemm3<0,0,1><<<dim3(8,128), dim3(256), 0, stream>>>(hdh, hdl, wth, wtl, b1b, out, out, nullptr, nullptr);
    }
}

// Round 10
// 1529.468 us; speedup vs baseline: 1.5487x; 1.2007x over previous
//
#include <hip/hip_runtime.h>

#define B 2
#define NQ 4096
#define NA 2048
#define CH 1024  // attention chunk (8 chunks)
#define LDK 40   // LDS row stride (shorts)

typedef __attribute__((ext_vector_type(8))) short bf16x8;
typedef __attribute__((ext_vector_type(4))) float f32x4;

__device__ __forceinline__ float b2f(unsigned short u){ union{unsigned i; float f;} c; c.i=((unsigned)u)<<16; return c.f; }
__device__ __forceinline__ unsigned short f2b(float f){ union{float f; unsigned u;} c; c.f=f; unsigned u=c.u; u += 0x7FFFu + ((u>>16)&1u); return (unsigned short)(u>>16); }
__device__ __forceinline__ void split2(float x, short& h, short& l){
    unsigned short hh = f2b(x); h = (short)hh; l = (short)f2b(x - b2f(hh));
}
__device__ __forceinline__ float4 ld4(const float* p){ return *(const float4*)p; }

// ======================= small projections =======================
__global__ __launch_bounds__(256) void proj_small(
    const float* __restrict__ gf,
    const float* __restrict__ w_qs, const float* __restrict__ w_kg, const float* __restrict__ w_vg,
    float* __restrict__ q_attn, float* __restrict__ kgv, float* __restrict__ vgv)
{
    int mat = blockIdx.x >> 1, b = blockIdx.x & 1;
    const float* W = (mat==0) ? w_qs : (mat==1 ? w_kg : w_vg);
    float* O       = (mat==0) ? q_attn : (mat==1 ? kgv : vgv);
    __shared__ float sg[512];
    int t = threadIdx.x;
    for (int i=t;i<512;i+=256) sg[i] = gf[b*512+i];
    __syncthreads();
    for (int c=t;c<512;c+=256) {
        float acc = 0.f;
        for (int k=0;k<512;k++) acc = fmaf(sg[k], W[k*512+c], acc);
        O[b*512+c] = acc;
    }
}

// ======================= KNN: 1024 blocks, 8 q/block x 32 thr/q, tree merge =======================
__global__ __launch_bounds__(256) void knn_kernel(
    const float* __restrict__ xyz_q, const float* __restrict__ axyz, int* __restrict__ knn)
{
    __shared__ float sax[NA], say[NA], saz[NA];   // 24 KB
    __shared__ double cd[8*257];                  // 16.4 KB
    __shared__ int    ci[8*257];                  // 8.2 KB
    const int t = threadIdx.x;
    const int b  = blockIdx.x >> 9;               // 512 blocks/batch
    const int qi = t >> 5;                        // 0..7
    const int q  = ((blockIdx.x & 511) << 3) + qi;
    const int g  = t & 31;                        // 32 threads/query
    for (int i=t;i<NA;i+=256) {
        const float* ap = axyz + (size_t)(b*NA+i)*3;
        sax[i]=ap[0]; say[i]=ap[1]; saz[i]=ap[2];
    }
    __syncthreads();
    const double qx = (double)xyz_q[(size_t)(b*NQ+q)*3+0];
    const double qy = (double)xyz_q[(size_t)(b*NQ+q)*3+1];
    const double qz = (double)xyz_q[(size_t)(b*NQ+q)*3+2];
    const double qq = (qx*qx + qy*qy) + qz*qz;
    double best[8]; int bid[8];
    #pragma unroll
    for (int j=0;j<8;j++){ best[j]=1.0e300; bid[j]=0; }
    for (int jj=0; jj<64; jj++) {
        const int i = jj*32 + g;                  // conflict-free + broadcast
        double ax=(double)sax[i], ay=(double)say[i], az=(double)saz[i];
        double aa  = (ax*ax + ay*ay) + az*az;
        double dot = (qx*ax + qy*ay) + qz*az;
        double dd  = (qq + aa) - 2.0*dot;
        if (dd < best[7]) {
            best[7]=dd; bid[7]=i;
            #pragma unroll
            for (int j=7;j>0;--j) if (best[j] < best[j-1]) {
                double tf=best[j]; best[j]=best[j-1]; best[j-1]=tf;
                int ti=bid[j]; bid[j]=bid[j-1]; bid[j-1]=ti;
            }
        }
    }
    const int base = qi*257;
    #pragma unroll
    for (int j=0;j<8;j++){ cd[base+g*8+j]=best[j]; ci[base+g*8+j]=bid[j]; }
    // tree merge: 32 -> 16 -> 8 -> 4 -> 2 -> 1 sorted-8 lists
    for (int s=16; s>=1; s>>=1) {
        __syncthreads();
        if (g < s) {
            double la[8], lb[8]; int ia[8], ib[8];
            #pragma unroll
            for (int j=0;j<8;j++){ la[j]=cd[base+g*8+j]; ia[j]=ci[base+g*8+j];
                                   lb[j]=cd[base+(g+s)*8+j]; ib[j]=ci[base+(g+s)*8+j]; }
            double lo[8]; int io[8];
            int pa=0, pb=0;
            #pragma unroll
            for (int m=0;m<8;m++) {
                bool ta = (pb>=8) || (pa<8 && la[pa] <= lb[pb]);
                if (ta) { lo[m]=la[pa]; io[m]=ia[pa]; pa++; }
                else    { lo[m]=lb[pb]; io[m]=ib[pb]; pb++; }
            }
            #pragma unroll
            for (int j=0;j<8;j++){ cd[base+g*8+j]=lo[j]; ci[base+g*8+j]=io[j]; }
        }
    }
    __syncthreads();
    if (g < 8) knn[(size_t)(b*NQ+q)*8+g] = ci[base+g];
}

// ======================= weight prep: W[k][n] fp32 -> [n][k] hi/lo bf16 =======================
__global__ __launch_bounds__(256) void prep_w(
    const float* __restrict__ W, short* __restrict__ Wh, short* __restrict__ Wl)
{
    const int gid = blockIdx.x*256 + threadIdx.x;
    const int n  = gid & 511;
    const int kc = (gid >> 9) * 8;
    short hi[8], lo[8];
    #pragma unroll
    for (int j=0;j<8;j++) split2(W[(size_t)(kc+j)*512 + n], hi[j], lo[j]);
    *(short4*)&Wh[(size_t)n*512 + kc]     = make_short4(hi[0],hi[1],hi[2],hi[3]);
    *(short4*)&Wh[(size_t)n*512 + kc + 4] = make_short4(hi[4],hi[5],hi[6],hi[7]);
    *(short4*)&Wl[(size_t)n*512 + kc]     = make_short4(lo[0],lo[1],lo[2],lo[3]);
    *(short4*)&Wl[(size_t)n*512 + kc + 4] = make_short4(lo[4],lo[5],lo[6],lo[7]);
}

// ======================= activation split: fp32 -> hi/lo bf16 =======================
__global__ __launch_bounds__(256) void split_fp32(
    const float* __restrict__ X, short* __restrict__ Xh, short* __restrict__ Xl)
{
    const size_t i0 = ((size_t)blockIdx.x*256 + threadIdx.x)*8;
    float4 a = *(const float4*)(X+i0), bq = *(const float4*)(X+i0+4);
    float v[8] = {a.x,a.y,a.z,a.w,bq.x,bq.y,bq.z,bq.w};
    short h[8], l[8];
    #pragma unroll
    for (int j=0;j<8;j++) split2(v[j], h[j], l[j]);
    *(short4*)(Xh+i0)   = make_short4(h[0],h[1],h[2],h[3]);
    *(short4*)(Xh+i0+4) = make_short4(h[4],h[5],h[6],h[7]);
    *(short4*)(Xl+i0)   = make_short4(l[0],l[1],l[2],l[3]);
    *(short4*)(Xl+i0+4) = make_short4(l[4],l[5],l[6],l[7]);
}

// ======================= x3 MFMA GEMM (A hi/lo): 64x64 block, 32x32 wave =======================
// OUT_MODE: 0=fp32; 1=split bf16; 2=fp32 + split(relu(v)); 3=single bf16
template<int OUT_MODE, int RELU_OUT, int HAS_ADD>
__global__ __launch_bounds__(256) void gemm3(
    const short* __restrict__ Ah, const short* __restrict__ Al,
    const short* __restrict__ Wh, const short* __restrict__ Wl,
    const float* __restrict__ bias, const float* __restrict__ addend,
    float* __restrict__ Cf, short* __restrict__ Ch, short* __restrict__ Cl)
{
    __shared__ short As_h[64*LDK], As_l[64*LDK], Bs_h[64*LDK], Bs_l[64*LDK];
    const int t = threadIdx.x;
    const int row0 = blockIdx.y*64, col0 = blockIdx.x*64;
    const int lane = t & 63, w = t >> 6;
    const int m0 = (w>>1)*32, n0 = (w&1)*32;
    const int fl = lane & 15, quad = lane >> 4;
    const int s_row = t >> 2, s_k = (t & 3) * 8;

    f32x4 zero = {0.f,0.f,0.f,0.f};
    f32x4 acc[2][2];
    acc[0][0]=zero; acc[0][1]=zero; acc[1][0]=zero; acc[1][1]=zero;

    for (int k0 = 0; k0 < 512; k0 += 32) {
        *(int4*)&As_h[s_row*LDK + s_k] = *(const int4*)(Ah + (size_t)(row0+s_row)*512 + k0 + s_k);
        *(int4*)&As_l[s_row*LDK + s_k] = *(const int4*)(Al + (size_t)(row0+s_row)*512 + k0 + s_k);
        *(int4*)&Bs_h[s_row*LDK + s_k] = *(const int4*)(Wh + (size_t)(col0+s_row)*512 + k0 + s_k);
        *(int4*)&Bs_l[s_row*LDK + s_k] = *(const int4*)(Wl + (size_t)(col0+s_row)*512 + k0 + s_k);
        __syncthreads();
        bf16x8 fah[2], fal[2], fbh[2], fbl[2];
        #pragma unroll
        for (int i=0;i<2;i++) {
            fah[i] = *(const bf16x8*)&As_h[(m0 + i*16 + fl)*LDK + quad*8];
            fal[i] = *(const bf16x8*)&As_l[(m0 + i*16 + fl)*LDK + quad*8];
            fbh[i] = *(const bf16x8*)&Bs_h[(n0 + i*16 + fl)*LDK + quad*8];
            fbl[i] = *(const bf16x8*)&Bs_l[(n0 + i*16 + fl)*LDK + quad*8];
        }
        #pragma unroll
        for (int i=0;i<2;i++)
        #pragma unroll
        for (int j=0;j<2;j++)
            acc[i][j] = __builtin_amdgcn_mfma_f32_16x16x32_bf16(fah[i], fbh[j], acc[i][j], 0,0,0);
        #pragma unroll
        for (int i=0;i<2;i++)
        #pragma unroll
        for (int j=0;j<2;j++)
            acc[i][j] = __builtin_amdgcn_mfma_f32_16x16x32_bf16(fah[i], fbl[j], acc[i][j], 0,0,0);
        #pragma unroll
        for (int i=0;i<2;i++)
        #pragma unroll
        for (int j=0;j<2;j++)
            acc[i][j] = __builtin_amdgcn_mfma_f32_16x16x32_bf16(fal[i], fbh[j], acc[i][j], 0,0,0);
        __syncthreads();
    }
    #pragma unroll
    for (int i=0;i<2;i++)
    #pragma unroll
    for (int j=0;j<2;j++) {
        const int col = col0 + n0 + j*16 + fl;
        const float bb = bias ? bias[col] : 0.f;
        #pragma unroll
        for (int r=0;r<4;r++) {
            const int row = row0 + m0 + i*16 + quad*4 + r;
            const size_t off = (size_t)row*512 + col;
            float v = acc[i][j][r] + bb;
            if (HAS_ADD) v += addend[off];
            if (OUT_MODE == 0) {
                if (RELU_OUT) v = fmaxf(v,0.f);
                Cf[off] = v;
            } else if (OUT_MODE == 1) {
                if (RELU_OUT) v = fmaxf(v,0.f);
                short h,l; split2(v,h,l); Ch[off]=h; Cl[off]=l;
            } else if (OUT_MODE == 2) {
                Cf[off] = v;
                short h,l; split2(fmaxf(v,0.f),h,l); Ch[off]=h; Cl[off]=l;
            } else {
                if (RELU_OUT) v = fmaxf(v,0.f);
                Ch[off] = (short)f2b(v);
            }
        }
    }
}

// ======================= x2 MFMA GEMM core (A bf16 in As LDS; caller stages A) ===============
// Shared inner for gemm2 / fused variants via macro-ish structure: here as plain kernels.

// plain x2 gemm: A from global single bf16
template<int OUT_MODE, int RELU_OUT>
__global__ __launch_bounds__(256) void gemm2(
    const short* __restrict__ Ab,
    const short* __restrict__ Wh, const short* __restrict__ Wl,
    const float* __restrict__ bias,
    float* __restrict__ Cf, short* __restrict__ Cb)
{
    __shared__ short As[64*LDK], Bs_h[64*LDK], Bs_l[64*LDK];
    const int t = threadIdx.x;
    const int row0 = blockIdx.y*64, col0 = blockIdx.x*64;
    const int lane = t & 63, w = t >> 6;
    const int m0 = (w>>1)*32, n0 = (w&1)*32;
    const int fl = lane & 15, quad = lane >> 4;
    const int s_row = t >> 2, s_k = (t & 3) * 8;

    f32x4 zero = {0.f,0.f,0.f,0.f};
    f32x4 acc[2][2];
    acc[0][0]=zero; acc[0][1]=zero; acc[1][0]=zero; acc[1][1]=zero;

    for (int k0 = 0; k0 < 512; k0 += 32) {
        *(int4*)&As[s_row*LDK + s_k]   = *(const int4*)(Ab + (size_t)(row0+s_row)*512 + k0 + s_k);
        *(int4*)&Bs_h[s_row*LDK + s_k] = *(const int4*)(Wh + (size_t)(col0+s_row)*512 + k0 + s_k);
        *(int4*)&Bs_l[s_row*LDK + s_k] = *(const int4*)(Wl + (size_t)(col0+s_row)*512 + k0 + s_k);
        __syncthreads();
        bf16x8 fa[2], fbh[2], fbl[2];
        #pragma unroll
        for (int i=0;i<2;i++) {
            fa[i]  = *(const bf16x8*)&As[(m0 + i*16 + fl)*LDK + quad*8];
            fbh[i] = *(const bf16x8*)&Bs_h[(n0 + i*16 + fl)*LDK + quad*8];
            fbl[i] = *(const bf16x8*)&Bs_l[(n0 + i*16 + fl)*LDK + quad*8];
        }
        #pragma unroll
        for (int i=0;i<2;i++)
        #pragma unroll
        for (int j=0;j<2;j++)
            acc[i][j] = __builtin_amdgcn_mfma_f32_16x16x32_bf16(fa[i], fbh[j], acc[i][j], 0,0,0);
        #pragma unroll
        for (int i=0;i<2;i++)
        #pragma unroll
        for (int j=0;j<2;j++)
            acc[i][j] = __builtin_amdgcn_mfma_f32_16x16x32_bf16(fa[i], fbl[j], acc[i][j], 0,0,0);
        __syncthreads();
    }
    #pragma unroll
    for (int i=0;i<2;i++)
    #pragma unroll
    for (int j=0;j<2;j++) {
        const int col = col0 + n0 + j*16 + fl;
        const float bb = bias ? bias[col] : 0.f;
        #pragma unroll
        for (int r=0;r<4;r++) {
            const int row = row0 + m0 + i*16 + quad*4 + r;
            const size_t off = (size_t)row*512 + col;
            float v = acc[i][j][r] + bb;
            if (RELU_OUT) v = fmaxf(v,0.f);
            if (OUT_MODE == 0) Cf[off] = v;
            else               Cb[off] = (short)f2b(v);
        }
    }
}

// fused pos GEMM: A = relu(d @ d1w + d1b) generated in staging; x2; out bf16 (bias=d2_b)
__global__ __launch_bounds__(256) void gemm_pos(
    const float* __restrict__ xyz_q, const float* __restrict__ axyz, const int* __restrict__ knn,
    const float* __restrict__ d1w, const float* __restrict__ d1b,
    const short* __restrict__ Wh, const short* __restrict__ Wl,
    const float* __restrict__ bias, short* __restrict__ Cb, int qbase)
{
    __shared__ short As[64*LDK], Bs_h[64*LDK], Bs_l[64*LDK];
    __shared__ float sdx[64], sdy[64], sdz[64];
    const int t = threadIdx.x;
    const int row0 = blockIdx.y*64, col0 = blockIdx.x*64;
    const int lane = t & 63, w = t >> 6;
    const int m0 = (w>>1)*32, n0 = (w&1)*32;
    const int fl = lane & 15, quad = lane >> 4;
    const int s_row = t >> 2, s_k = (t & 3) * 8;
    if (t < 64) {
        int gr = qbase*8 + row0 + t;
        int b  = gr >> 15;
        int gq = gr >> 3;
        int idx = knn[gr];
        const float* qp = xyz_q + (size_t)gq*3;
        const float* ap = axyz + (size_t)(b*NA + idx)*3;
        sdx[t]=qp[0]-ap[0]; sdy[t]=qp[1]-ap[1]; sdz[t]=qp[2]-ap[2];
    }
    __syncthreads();
    const float dx = sdx[s_row], dy = sdy[s_row], dz = sdz[s_row];

    f32x4 zero = {0.f,0.f,0.f,0.f};
    f32x4 acc[2][2];
    acc[0][0]=zero; acc[0][1]=zero; acc[1][0]=zero; acc[1][1]=zero;

    for (int k0 = 0; k0 < 512; k0 += 32) {
        {
            const int k = k0 + s_k;
            float4 w0a = ld4(d1w + k),        w0b = ld4(d1w + k + 4);
            float4 w1a = ld4(d1w + 512 + k),  w1b = ld4(d1w + 512 + k + 4);
            float4 w2a = ld4(d1w + 1024 + k), w2b = ld4(d1w + 1024 + k + 4);
            float4 bba = ld4(d1b + k),        bbb = ld4(d1b + k + 4);
            float v[8];
            v[0]=fmaf(dx,w0a.x,fmaf(dy,w1a.x,fmaf(dz,w2a.x,bba.x)));
            v[1]=fmaf(dx,w0a.y,fmaf(dy,w1a.y,fmaf(dz,w2a.y,bba.y)));
            v[2]=fmaf(dx,w0a.z,fmaf(dy,w1a.z,fmaf(dz,w2a.z,bba.z)));
            v[3]=fmaf(dx,w0a.w,fmaf(dy,w1a.w,fmaf(dz,w2a.w,bba.w)));
            v[4]=fmaf(dx,w0b.x,fmaf(dy,w1b.x,fmaf(dz,w2b.x,bbb.x)));
            v[5]=fmaf(dx,w0b.y,fmaf(dy,w1b.y,fmaf(dz,w2b.y,bbb.y)));
            v[6]=fmaf(dx,w0b.z,fmaf(dy,w1b.z,fmaf(dz,w2b.z,bbb.z)));
            v[7]=fmaf(dx,w0b.w,fmaf(dy,w1b.w,fmaf(dz,w2b.w,bbb.w)));
            short o[8];
            #pragma unroll
            for (int j=0;j<8;j++) o[j] = (short)f2b(fmaxf(v[j],0.f));
            *(short4*)&As[s_row*LDK + s_k]     = make_short4(o[0],o[1],o[2],o[3]);
            *(short4*)&As[s_row*LDK + s_k + 4] = make_short4(o[4],o[5],o[6],o[7]);
        }
        *(int4*)&Bs_h[s_row*LDK + s_k] = *(const int4*)(Wh + (size_t)(col0+s_row)*512 + k0 + s_k);
        *(int4*)&Bs_l[s_row*LDK + s_k] = *(const int4*)(Wl + (size_t)(col0+s_row)*512 + k0 + s_k);
        __syncthreads();
        bf16x8 fa[2], fbh[2], fbl[2];
        #pragma unroll
        for (int i=0;i<2;i++) {
            fa[i]  = *(const bf16x8*)&As[(m0 + i*16 + fl)*LDK + quad*8];
            fbh[i] = *(const bf16x8*)&Bs_h[(n0 + i*16 + fl)*LDK + quad*8];
            fbl[i] = *(const bf16x8*)&Bs_l[(n0 + i*16 + fl)*LDK + quad*8];
        }
        #pragma unroll
        for (int i=0;i<2;i++)
        #pragma unroll
        for (int j=0;j<2;j++)
            acc[i][j] = __builtin_amdgcn_mfma_f32_16x16x32_bf16(fa[i], fbh[j], acc[i][j], 0,0,0);
        #pragma unroll
        for (int i=0;i<2;i++)
        #pragma unroll
        for (int j=0;j<2;j++)
            acc[i][j] = __builtin_amdgcn_mfma_f32_16x16x32_bf16(fa[i], fbl[j], acc[i][j], 0,0,0);
        __syncthreads();
    }
    #pragma unroll
    for (int i=0;i<2;i++)
    #pragma unroll
    for (int j=0;j<2;j++) {
        const int col = col0 + n0 + j*16 + fl;
        const float bb = bias[col];
        #pragma unroll
        for (int r=0;r<4;r++) {
            const int row = row0 + m0 + i*16 + quad*4 + r;
            Cb[(size_t)row*512 + col] = (short)f2b(acc[i][j][r] + bb);
        }
    }
}

// fused g1 GEMM: A = (q_attn - k + pos) assembled in staging; x2; relu; out bf16
__global__ __launch_bounds__(256) void gemm_g1(
    const float* __restrict__ q_attn, const float* __restrict__ kgv,
    const short* __restrict__ ak_bf, const short* __restrict__ pos_bf, const int* __restrict__ knn,
    const short* __restrict__ Wh, const short* __restrict__ Wl,
    const float* __restrict__ bias, short* __restrict__ Cb, int qbase)
{
    __shared__ short As[64*LDK], Bs_h[64*LDK], Bs_l[64*LDK];
    __shared__ int s_aoff[64], s_poff[64];
    const int t = threadIdx.x;
    const int row0 = blockIdx.y*64, col0 = blockIdx.x*64;
    const int lane = t & 63, w = t >> 6;
    const int m0 = (w>>1)*32, n0 = (w&1)*32;
    const int fl = lane & 15, quad = lane >> 4;
    const int s_row = t >> 2, s_k = (t & 3) * 8;
    const int b = qbase >> 12;
    if (t < 64) {
        int g = row0 + t;
        int q = g / 9, n = g - q*9;
        if (n < 8) { s_aoff[t] = b*NA + knn[(size_t)(qbase + q)*8 + n]; s_poff[t] = q*8 + n; }
        else       { s_aoff[t] = -1; s_poff[t] = 0; }
    }
    __syncthreads();
    const int ao = s_aoff[s_row];
    const int po = s_poff[s_row];

    f32x4 zero = {0.f,0.f,0.f,0.f};
    f32x4 acc[2][2];
    acc[0][0]=zero; acc[0][1]=zero; acc[1][0]=zero; acc[1][1]=zero;

    for (int k0 = 0; k0 < 512; k0 += 32) {
        {
            const int k = k0 + s_k;
            float4 qa0 = ld4(q_attn + b*512 + k), qa1 = ld4(q_attn + b*512 + k + 4);
            float v[8];
            if (ao >= 0) {
                ushort4 k0v = *(const ushort4*)(ak_bf + (size_t)ao*512 + k);
                ushort4 k1v = *(const ushort4*)(ak_bf + (size_t)ao*512 + k + 4);
                ushort4 p0v = *(const ushort4*)(pos_bf + (size_t)po*512 + k);
                ushort4 p1v = *(const ushort4*)(pos_bf + (size_t)po*512 + k + 4);
                v[0]=qa0.x-b2f(k0v.x)+b2f(p0v.x); v[1]=qa0.y-b2f(k0v.y)+b2f(p0v.y);
                v[2]=qa0.z-b2f(k0v.z)+b2f(p0v.z); v[3]=qa0.w-b2f(k0v.w)+b2f(p0v.w);
                v[4]=qa1.x-b2f(k1v.x)+b2f(p1v.x); v[5]=qa1.y-b2f(k1v.y)+b2f(p1v.y);
                v[6]=qa1.z-b2f(k1v.z)+b2f(p1v.z); v[7]=qa1.w-b2f(k1v.w)+b2f(p1v.w);
            } else {
                float4 g0 = ld4(kgv + b*512 + k), g1 = ld4(kgv + b*512 + k + 4);
                v[0]=qa0.x-g0.x; v[1]=qa0.y-g0.y; v[2]=qa0.z-g0.z; v[3]=qa0.w-g0.w;
                v[4]=qa1.x-g1.x; v[5]=qa1.y-g1.y; v[6]=qa1.z-g1.z; v[7]=qa1.w-g1.w;
            }
            short o[8];
            #pragma unroll
            for (int j=0;j<8;j++) o[j] = (short)f2b(v[j]);
            *(short4*)&As[s_row*LDK + s_k]     = make_short4(o[0],o[1],o[2],o[3]);
            *(short4*)&As[s_row*LDK + s_k + 4] = make_short4(o[4],o[5],o[6],o[7]);
        }
        *(int4*)&Bs_h[s_row*LDK + s_k] = *(const int4*)(Wh + (size_t)(col0+s_row)*512 + k0 + s_k);
        *(int4*)&Bs_l[s_row*LDK + s_k] = *(const int4*)(Wl + (size_t)(col0+s_row)*512 + k0 + s_k);
        __syncthreads();
        bf16x8 fa[2], fbh[2], fbl[2];
        #pragma unroll
        for (int i=0;i<2;i++) {
            fa[i]  = *(const bf16x8*)&As[(m0 + i*16 + fl)*LDK + quad*8];
            fbh[i] = *(const bf16x8*)&Bs_h[(n0 + i*16 + fl)*LDK + quad*8];
            fbl[i] = *(const bf16x8*)&Bs_l[(n0 + i*16 + fl)*LDK + quad*8];
        }
        #pragma unroll
        for (int i=0;i<2;i++)
        #pragma unroll
        for (int j=0;j<2;j++)
            acc[i][j] = __builtin_amdgcn_mfma_f32_16x16x32_bf16(fa[i], fbh[j], acc[i][j], 0,0,0);
        #pragma unroll
        for (int i=0;i<2;i++)
        #pragma unroll
        for (int j=0;j<2;j++)
            acc[i][j] = __builtin_amdgcn_mfma_f32_16x16x32_bf16(fa[i], fbl[j], acc[i][j], 0,0,0);
        __syncthreads();
    }
    #pragma unroll
    for (int i=0;i<2;i++)
    #pragma unroll
    for (int j=0;j<2;j++) {
        const int col = col0 + n0 + j*16 + fl;
        const float bb = bias[col];
        #pragma unroll
        for (int r=0;r<4;r++) {
            const int row = row0 + m0 + i*16 + quad*4 + r;
            Cb[(size_t)row*512 + col] = (short)f2b(fmaxf(acc[i][j][r] + bb, 0.f));
        }
    }
}

// ======================= softmax + aggregation (bf16 attn_pre) =======================
__global__ __launch_bounds__(256) void softmax_agg(
    const short* __restrict__ attn_preb, const short* __restrict__ pos_bf,
    const short* __restrict__ av_bf, const float* __restrict__ vgv,
    const int* __restrict__ knn, short* __restrict__ lath, short* __restrict__ latl, int qbase)
{
    __shared__ int sk[8];
    const int q = blockIdx.x;
    const int gq = qbase + q;
    const int b = qbase >> 12;
    const int t = threadIdx.x;
    if (t < 8) sk[t] = knn[(size_t)gq*8 + t];
    __syncthreads();
    for (int c = t; c < 512; c += 256) {
        float p[9];
        #pragma unroll
        for (int n=0;n<9;n++) p[n] = b2f((unsigned short)attn_preb[(size_t)(q*9+n)*512 + c]);
        float m = p[0];
        #pragma unroll
        for (int n=1;n<9;n++) m = fmaxf(m, p[n]);
        float e[9], s = 0.f;
        #pragma unroll
        for (int n=0;n<9;n++){ e[n] = expf(p[n]-m); s += e[n]; }
        const float inv = 1.0f / s;
        float acc = 0.f;
        #pragma unroll
        for (int n=0;n<8;n++) {
            float vv = b2f((unsigned short)av_bf[(size_t)(b*NA + sk[n])*512 + c])
                     + b2f((unsigned short)pos_bf[(size_t)(q*8+n)*512 + c]);
            acc = fmaf(e[n]*inv, vv, acc);
        }
        acc = fmaf(e[8]*inv, vgv[b*512 + c], acc);
        short h,l; split2(acc,h,l);
        lath[(size_t)gq*512 + c] = h; latl[(size_t)gq*512 + c] = l;
    }
}

// ======================= PE + first decoder layer =======================
__global__ __launch_bounds__(256) void pe_fc(
    const float* __restrict__ xyz_q, const float* __restrict__ fw, const float* __restrict__ fb,
    float* __restrict__ net)
{
    __shared__ float spe[16*60];
    const int t = threadIdx.x;
    const int q0 = blockIdx.x * 16;
    for (int i=t;i<960;i+=256) {
        int ql = i/60, j = i - ql*60;
        int l = j/6; int r6 = j - l*6; int s = r6/3; int d = r6 - s*3;
        float pv = xyz_q[(size_t)(q0+ql)*3 + d];
        float a = pv * (3.14159265358979323846f * (float)(1<<l));
        spe[ql*60+j] = (s==0) ? sinf(a) : cosf(a);
    }
    __syncthreads();
    float acc0[16], acc1[16];
    #pragma unroll
    for (int ql=0;ql<16;ql++){ acc0[ql]=0.f; acc1[ql]=0.f; }
    const int c0 = t, c1 = t + 256;
    for (int k=0;k<60;k++) {
        float w0 = fw[k*512 + c0];
        float w1 = fw[k*512 + c1];
        #pragma unroll
        for (int ql=0;ql<16;ql++) {
            float pv = spe[ql*60+k];
            acc0[ql] = fmaf(pv, w0, acc0[ql]);
            acc1[ql] = fmaf(pv, w1, acc1[ql]);
        }
    }
    const float b0v = fb[c0], b1v = fb[c1];
    #pragma unroll
    for (int ql=0;ql<16;ql++) {
        net[(size_t)(q0+ql)*512 + c0] = acc0[ql] + b0v;
        net[(size_t)(q0+ql)*512 + c1] = acc1[ql] + b1v;
    }
}

// ======================= launch =======================
extern "C" void kernel_launch(void* const* d_in, const int* in_sizes, int n_in,
                              void* d_out, int out_size, void* d_ws, size_t ws_size,
                              hipStream_t stream) {
    const float* xyz_q  = (const float*)d_in[0];
    const float* gf     = (const float*)d_in[1];
    const float* axyz   = (const float*)d_in[2];
    const float* afeat  = (const float*)d_in[3];
    const float* w_qs   = (const float*)d_in[4];
    const float* w_ks   = (const float*)d_in[5];
    const float* w_vs   = (const float*)d_in[6];
    const float* w_kg   = (const float*)d_in[7];
    const float* w_vg   = (const float*)d_in[8];
    const float* d1_w   = (const float*)d_in[9];
    const float* d1_b   = (const float*)d_in[10];
    const float* d2_w   = (const float*)d_in[11];
    const float* d2_b   = (const float*)d_in[12];
    const float* g1_w   = (const float*)d_in[13];
    const float* g1_b   = (const float*)d_in[14];
    const float* g2_w   = (const float*)d_in[15];
    const float* g2_b   = (const float*)d_in[16];
    const float* fc_p_w = (const float*)d_in[17];
    const float* fc_p_b = (const float*)d_in[18];
    const float* fc_c_w = (const float*)d_in[19];
    const float* fc_c_b = (const float*)d_in[20];
    const float* blk0_w = (const float*)d_in[21];
    const float* blk0_b = (const float*)d_in[22];
    const float* blk1_w = (const float*)d_in[23];
    const float* blk1_b = (const float*)d_in[24];
    float* out = (float*)d_out;

    const size_t MB = 1u<<20;
    char* base = (char*)d_ws;
    // ---- persistent (21 MB) ----
    float* q_attn = (float*)base;
    float* kgv    = q_attn + 1024;
    float* vgv    = kgv + 1024;
    int*   knn    = (int*)(base + 16*1024);
    short* wd2h = (short*)(base + 1*MB); short* wd2l = wd2h + 262144;
    short* wg1h = wd2l + 262144;         short* wg1l = wg1h + 262144;
    short* wg2h = wg1l + 262144;         short* wg2l = wg2h + 262144;
    short* wth  = wg2l + 262144;         short* wtl  = wth  + 262144;
    short* lath = (short*)(base + 5*MB);
    short* latl = (short*)(base + 13*MB);
    // ---- transient T (34 MB): total 55 MB ----
    char* T = base + 21*MB;
    short* ak_bf = (short*)T;                    // 4 MB
    short* av_bf = (short*)(T + 4*MB);           // 4 MB
    short* posb  = (short*)(T + 8*MB);           // 8 MB   (CH*8*512*2)
    short* yb    = (short*)(T + 16*MB);          // 9 MB   (CH*9*512*2)
    short* attn_preb = (short*)(T + 25*MB);      // 9 MB   (ends T+34MB)
    // phase A overlays (afeat split) — posb/yb regions are dead then
    short* afh = (short*)(T + 8*MB);
    short* afl = (short*)(T + 16*MB);
    // decoder overlays
    short* nrh = (short*)T;            short* nrl = (short*)(T + 8*MB);
    short* hdh = (short*)(T + 16*MB);  short* hdl = (short*)(T + 24*MB);
    if ((size_t)(55*MB) > ws_size) return;

    proj_small<<<dim3(6), dim3(256), 0, stream>>>(gf, w_qs, w_kg, w_vg, q_attn, kgv, vgv);
    knn_kernel<<<dim3(1024), dim3(256), 0, stream>>>(xyz_q, axyz, knn);

    split_fp32<<<dim3(1024), dim3(256), 0, stream>>>(afeat, afh, afl);
    prep_w<<<dim3(128), dim3(256), 0, stream>>>(w_ks, wth, wtl);
    gemm3<3,0,0><<<dim3(8,64), dim3(256), 0, stream>>>(afh, afl, wth, wtl, nullptr, nullptr, nullptr, ak_bf, nullptr);
    prep_w<<<dim3(128), dim3(256), 0, stream>>>(w_vs, wth, wtl);
    gemm3<3,0,0><<<dim3(8,64), dim3(256), 0, stream>>>(afh, afl, wth, wtl, nullptr, nullptr, nullptr, av_bf, nullptr);

    prep_w<<<dim3(128), dim3(256), 0, stream>>>(d2_w, wd2h, wd2l);
    prep_w<<<dim3(128), dim3(256), 0, stream>>>(g1_w, wg1h, wg1l);
    prep_w<<<dim3(128), dim3(256), 0, stream>>>(g2_w, wg2h, wg2l);

    for (int qbase = 0; qbase < B*NQ; qbase += CH) {
        gemm_pos<<<dim3(8, CH*8/64), dim3(256), 0, stream>>>(xyz_q, axyz, knn, d1_w, d1_b, wd2h, wd2l, d2_b, posb, qbase);
        gemm_g1<<<dim3(8, CH*9/64), dim3(256), 0, stream>>>(q_attn, kgv, ak_bf, posb, knn, wg1h, wg1l, g1_b, yb, qbase);
        gemm2<3,0><<<dim3(8, CH*9/64), dim3(256), 0, stream>>>(yb, wg2h, wg2l, g2_b, nullptr, attn_preb);
        softmax_agg<<<dim3(CH), dim3(256), 0, stream>>>(attn_preb, posb, av_bf, vgv, knn, lath, latl, qbase);
    }

    pe_fc<<<dim3(512), dim3(256), 0, stream>>>(xyz_q, fc_p_w, fc_p_b, out);
    for (int i=0;i<5;i++) {
        const float* cw  = fc_c_w + (size_t)i*512*512;
        const float* cb  = fc_c_b + (size_t)i*512;
        const float* b0w = blk0_w + (size_t)i*512*512;
        const float* b0b = blk0_b + (size_t)i*512;
        const float* b1w = blk1_w + (size_t)i*512*512;
        const float* b1b = blk1_b + (size_t)i*512;
        prep_w<<<dim3(128), dim3(256), 0, stream>>>(cw, wth, wtl);
        gemm3<2,0,1><<<dim3(8,128), dim3(256), 0, stream>>>(lath, latl, wth, wtl, cb, out, out, nrh, nrl);
        prep_w<<<dim3(128), dim3(256), 0, stream>>>(b0w, wth, wtl);
        gemm3<1,1,0><<<dim3(8,128), dim3(256), 0, stream>>>(nrh, nrl, wth, wtl, b0b, nullptr, nullptr, hdh, hdl);
        prep_w<<<dim3(128), dim3(256), 0, stream>>>(b1w, wth, wtl);
        gemm3<0,0,1><<<dim3(8,128), dim3(256), 0, stream>>>(hdh, hdl, wth, wtl, b1b, out, out, nullptr, nullptr);
    }
}